// Round 1
// baseline (306.867 us; speedup 1.0000x reference)
//
#include <hip/hip_runtime.h>

using u16 = unsigned short;
typedef __attribute__((ext_vector_type(8))) _Float16 half8;
typedef __attribute__((ext_vector_type(4))) float f32x4;
typedef __attribute__((ext_vector_type(4))) unsigned short u16x4;

#define S_LEN 2048
#define D_MODEL 1024
#define NHEAD 16
#define HDIM 64

__device__ __forceinline__ u16 f2h_bits(float f){
    _Float16 h = (_Float16)f;
    return __builtin_bit_cast(u16, h);
}

// ---------- x fp32 -> fp16 ----------
__global__ __launch_bounds__(256) void k_cvt_x(const float* __restrict__ x, u16* __restrict__ xh){
    int i = blockIdx.x*256 + threadIdx.x;
    float4 v = reinterpret_cast<const float4*>(x)[i];
    u16x4 o;
    o.x = f2h_bits(v.x); o.y = f2h_bits(v.y); o.z = f2h_bits(v.z); o.w = f2h_bits(v.w);
    reinterpret_cast<u16x4*>(xh)[i] = o;
}

// ---------- W [K][N] fp32 -> WT [N][K] fp16 (transpose via LDS) ----------
__global__ __launch_bounds__(256) void k_cvt_wT(const float* __restrict__ W, u16* __restrict__ WT,
                                                int K, int N){
    __shared__ float t[32][33];
    int tx = threadIdx.x & 31, ty = threadIdx.x >> 5;   // 32 x 8
    int n0 = blockIdx.x*32, k0 = blockIdx.y*32;
    #pragma unroll
    for (int i=0;i<4;++i) t[ty+8*i][tx] = W[(size_t)(k0+ty+8*i)*N + n0+tx];
    __syncthreads();
    #pragma unroll
    for (int i=0;i<4;++i) WT[(size_t)(n0+ty+8*i)*K + k0+tx] = f2h_bits(t[tx][ty+8*i]);
}

// ---------- GEMM: C[M,N] = A[M,1024] * BT[N,1024]^T, fp16 in / fp32 acc ----------
// EPI 0: write fp32 C (stride D_MODEL).  EPI 1: scatter QKV (Q,K row-major per head; V transposed).
template<int EPI>
__global__ __launch_bounds__(256) void k_gemm(const u16* __restrict__ A, const u16* __restrict__ BT,
                                              float* __restrict__ Cf, u16* __restrict__ Qh,
                                              u16* __restrict__ Kh, u16* __restrict__ Vt){
    constexpr int Kd = 1024;
    int w    = threadIdx.x >> 6;
    int lane = threadIdx.x & 63;
    int lr = lane & 15, lg = lane >> 4;
    int m0 = blockIdx.y*128 + (w>>1)*64;
    int n0 = blockIdx.x*128 + (w&1)*64;
    const u16* Ab = A  + (size_t)(m0+lr)*Kd + lg*8;
    const u16* Bb = BT + (size_t)(n0+lr)*Kd + lg*8;
    f32x4 acc[4][4];
    #pragma unroll
    for (int i=0;i<4;++i)
        #pragma unroll
        for (int j=0;j<4;++j) acc[i][j] = (f32x4){0.f,0.f,0.f,0.f};

    for (int kk=0; kk<Kd; kk+=32){
        half8 av[4], bv[4];
        #pragma unroll
        for (int mf=0;mf<4;++mf) av[mf] = *reinterpret_cast<const half8*>(Ab + (size_t)mf*16*Kd + kk);
        #pragma unroll
        for (int nf=0;nf<4;++nf) bv[nf] = *reinterpret_cast<const half8*>(Bb + (size_t)nf*16*Kd + kk);
        #pragma unroll
        for (int mf=0;mf<4;++mf)
            #pragma unroll
            for (int nf=0;nf<4;++nf)
                acc[mf][nf] = __builtin_amdgcn_mfma_f32_16x16x32_f16(av[mf], bv[nf], acc[mf][nf], 0,0,0);
    }

    if (EPI == 0){
        #pragma unroll
        for (int mf=0;mf<4;++mf)
            #pragma unroll
            for (int nf=0;nf<4;++nf)
                #pragma unroll
                for (int j=0;j<4;++j)
                    Cf[(size_t)(m0+mf*16+lg*4+j)*D_MODEL + n0+nf*16+lr] = acc[mf][nf][j];
    } else {
        #pragma unroll
        for (int mf=0;mf<4;++mf){
            int r0 = m0 + mf*16 + lg*4;          // 4 consecutive global rows
            int b  = r0 >> 11, s = r0 & 2047;    // same b for all 4 (2048-aligned boundary)
            #pragma unroll
            for (int nf=0;nf<4;++nf){
                int col = n0 + nf*16 + lr;       // 0..3071
                int which = col >> 10;
                int d  = col & 1023;
                int h  = d >> 6, di = d & 63;
                int bh = b*NHEAD + h;
                if (which == 2){
                    u16x4 pv;
                    pv.x = f2h_bits(acc[mf][nf][0]);
                    pv.y = f2h_bits(acc[mf][nf][1]);
                    pv.z = f2h_bits(acc[mf][nf][2]);
                    pv.w = f2h_bits(acc[mf][nf][3]);
                    *reinterpret_cast<u16x4*>(Vt + ((size_t)bh*HDIM + di)*S_LEN + s) = pv;
                } else {
                    u16* dst = (which==0 ? Qh : Kh) + ((size_t)bh*S_LEN + s)*HDIM + di;
                    #pragma unroll
                    for (int j=0;j<4;++j) dst[(size_t)j*HDIM] = f2h_bits(acc[mf][nf][j]);
                }
            }
        }
    }
}

// ---------- flash attention: 1 wave per block, 32 q-rows, k-tiles of 32 ----------
__global__ __launch_bounds__(64) void k_attn(const u16* __restrict__ Q, const u16* __restrict__ K,
                                             const u16* __restrict__ Vt, u16* __restrict__ Mg){
    __shared__ u16 plds[32][40];                 // +8 pad: conflict-free b128 reads
    int blk = blockIdx.x;
    int qb = blk & 63;                           // q-tile index (32 rows each)
    int bh = blk >> 6;                           // 0..31
    int b = bh >> 4, h = bh & 15;
    int lane = threadIdx.x;
    int lr = lane & 15, lg = lane >> 4;
    int q0 = qb*32;
    const u16* Qp = Q  + (size_t)bh*S_LEN*HDIM;
    const u16* Kp = K  + (size_t)bh*S_LEN*HDIM;
    const u16* Vp = Vt + (size_t)bh*HDIM*S_LEN;

    half8 qf[2][2];
    #pragma unroll
    for (int mf=0;mf<2;++mf)
        #pragma unroll
        for (int ks=0;ks<2;++ks)
            qf[mf][ks] = *reinterpret_cast<const half8*>(Qp + (size_t)(q0+mf*16+lr)*HDIM + ks*32 + lg*8);

    f32x4 oacc[2][4];
    float mrow[2][4], lrow[2][4];
    #pragma unroll
    for (int mf=0;mf<2;++mf){
        #pragma unroll
        for (int nf=0;nf<4;++nf) oacc[mf][nf] = (f32x4){0.f,0.f,0.f,0.f};
        #pragma unroll
        for (int j=0;j<4;++j){ mrow[mf][j] = -1e30f; lrow[mf][j] = 0.f; }
    }

    for (int kt=0; kt<=qb; ++kt){
        int kbase = kt*32;
        f32x4 sc[2][2];
        #pragma unroll
        for (int mf=0;mf<2;++mf)
            #pragma unroll
            for (int nf=0;nf<2;++nf) sc[mf][nf] = (f32x4){0.f,0.f,0.f,0.f};
        half8 kf[2][2];
        #pragma unroll
        for (int nf=0;nf<2;++nf)
            #pragma unroll
            for (int ks=0;ks<2;++ks)
                kf[nf][ks] = *reinterpret_cast<const half8*>(Kp + (size_t)(kbase+nf*16+lr)*HDIM + ks*32 + lg*8);
        #pragma unroll
        for (int mf=0;mf<2;++mf)
            #pragma unroll
            for (int nf=0;nf<2;++nf)
                #pragma unroll
                for (int ks=0;ks<2;++ks)
                    sc[mf][nf] = __builtin_amdgcn_mfma_f32_16x16x32_f16(qf[mf][ks], kf[nf][ks], sc[mf][nf], 0,0,0);

        if (kt == qb){   // diagonal tile: causal mask, matches ref's -1e9 semantics
            #pragma unroll
            for (int mf=0;mf<2;++mf)
                #pragma unroll
                for (int nf=0;nf<2;++nf)
                    #pragma unroll
                    for (int j=0;j<4;++j)
                        if (kbase+nf*16+lr > q0+mf*16+lg*4+j) sc[mf][nf][j] = -1e9f;
        }

        float alpha[2][4];
        #pragma unroll
        for (int mf=0;mf<2;++mf)
            #pragma unroll
            for (int j=0;j<4;++j){
                float t = fmaxf(sc[mf][0][j], sc[mf][1][j]);
                t = fmaxf(t, __shfl_xor(t,1));
                t = fmaxf(t, __shfl_xor(t,2));
                t = fmaxf(t, __shfl_xor(t,4));
                t = fmaxf(t, __shfl_xor(t,8));
                float mnew = fmaxf(mrow[mf][j], t);
                alpha[mf][j] = __expf(mrow[mf][j] - mnew);
                mrow[mf][j] = mnew;
            }
        #pragma unroll
        for (int mf=0;mf<2;++mf)
            #pragma unroll
            for (int nf=0;nf<2;++nf)
                #pragma unroll
                for (int j=0;j<4;++j)
                    sc[mf][nf][j] = __expf(sc[mf][nf][j] - mrow[mf][j]);
        #pragma unroll
        for (int mf=0;mf<2;++mf)
            #pragma unroll
            for (int j=0;j<4;++j){
                float rs = sc[mf][0][j] + sc[mf][1][j];
                rs += __shfl_xor(rs,1);
                rs += __shfl_xor(rs,2);
                rs += __shfl_xor(rs,4);
                rs += __shfl_xor(rs,8);
                lrow[mf][j] = lrow[mf][j]*alpha[mf][j] + rs;
            }
        #pragma unroll
        for (int mf=0;mf<2;++mf)
            #pragma unroll
            for (int nf=0;nf<4;++nf)
                #pragma unroll
                for (int j=0;j<4;++j)
                    oacc[mf][nf][j] *= alpha[mf][j];

        __syncthreads();   // WAR: previous iter's plds reads done before overwrite
        #pragma unroll
        for (int mf=0;mf<2;++mf)
            #pragma unroll
            for (int nf=0;nf<2;++nf)
                #pragma unroll
                for (int j=0;j<4;++j)
                    plds[mf*16+lg*4+j][nf*16+lr] = f2h_bits(sc[mf][nf][j]);
        __syncthreads();

        half8 pa[2];
        #pragma unroll
        for (int mf=0;mf<2;++mf)
            pa[mf] = *reinterpret_cast<const half8*>(&plds[mf*16+lr][lg*8]);
        half8 vf[4];
        #pragma unroll
        for (int nf=0;nf<4;++nf)
            vf[nf] = *reinterpret_cast<const half8*>(Vp + (size_t)(nf*16+lr)*S_LEN + kbase + lg*8);
        #pragma unroll
        for (int mf=0;mf<2;++mf)
            #pragma unroll
            for (int nf=0;nf<4;++nf)
                oacc[mf][nf] = __builtin_amdgcn_mfma_f32_16x16x32_f16(pa[mf], vf[nf], oacc[mf][nf], 0,0,0);
    }

    float invl[2][4];
    #pragma unroll
    for (int mf=0;mf<2;++mf)
        #pragma unroll
        for (int j=0;j<4;++j) invl[mf][j] = 1.0f/lrow[mf][j];
    #pragma unroll
    for (int mf=0;mf<2;++mf)
        #pragma unroll
        for (int nf=0;nf<4;++nf)
            #pragma unroll
            for (int j=0;j<4;++j)
                Mg[(size_t)(b*S_LEN + q0 + mf*16 + lg*4 + j)*D_MODEL + h*HDIM + nf*16 + lr]
                    = f2h_bits(oacc[mf][nf][j]*invl[mf][j]);
}

extern "C" void kernel_launch(void* const* d_in, const int* in_sizes, int n_in,
                              void* d_out, int out_size, void* d_ws, size_t ws_size,
                              hipStream_t stream) {
    const float* x    = (const float*)d_in[0];
    const float* wqkv = (const float*)d_in[1];
    const float* wout = (const float*)d_in[2];
    float* out = (float*)d_out;
    char* ws = (char*)d_ws;

    const size_t MB = 1u<<20;
    u16* xh     = (u16*)(ws + 0*MB);    // 8 MiB  [4096][1024] fp16
    u16* wqkvT  = (u16*)(ws + 8*MB);    // 6 MiB  [3072][1024] fp16
    u16* woutT  = (u16*)(ws + 14*MB);   // 2 MiB  [1024][1024] fp16
    u16* Qh     = (u16*)(ws + 16*MB);   // 8 MiB  [b,h,s,d]
    u16* Kh     = (u16*)(ws + 24*MB);   // 8 MiB  [b,h,s,d]
    u16* Vt     = (u16*)(ws + 32*MB);   // 8 MiB  [b,h,d,s]  (transposed)
    u16* Mg     = (u16*)(ws + 40*MB);   // 8 MiB  merged [4096][1024] fp16

    k_cvt_x <<<4096, 256, 0, stream>>>(x, xh);
    k_cvt_wT<<<dim3(96,32), 256, 0, stream>>>(wqkv, wqkvT, 1024, 3072);
    k_cvt_wT<<<dim3(32,32), 256, 0, stream>>>(wout, woutT, 1024, 1024);
    k_gemm<1><<<dim3(24,32), 256, 0, stream>>>(xh, wqkvT, nullptr, Qh, Kh, Vt);
    k_attn  <<<2048, 64, 0, stream>>>(Qh, Kh, Vt, Mg);
    k_gemm<0><<<dim3(8,32), 256, 0, stream>>>(Mg, woutT, out, nullptr, nullptr, nullptr);
}

// Round 2
// 243.017 us; speedup vs baseline: 1.2627x; 1.2627x over previous
//
#include <hip/hip_runtime.h>

using u16 = unsigned short;
typedef __attribute__((ext_vector_type(8))) _Float16 half8;
typedef __attribute__((ext_vector_type(4))) float f32x4;
typedef __attribute__((ext_vector_type(4))) unsigned short u16x4;

#define S_LEN 2048
#define D_MODEL 1024
#define NHEAD 16
#define HDIM 64

__device__ __forceinline__ u16 f2h_bits(float f){
    _Float16 h = (_Float16)f;
    return __builtin_bit_cast(u16, h);
}

// ---------- x fp32 -> fp16 ----------
__global__ __launch_bounds__(256) void k_cvt_x(const float* __restrict__ x, u16* __restrict__ xh){
    int i = blockIdx.x*256 + threadIdx.x;
    float4 v = reinterpret_cast<const float4*>(x)[i];
    u16x4 o;
    o.x = f2h_bits(v.x); o.y = f2h_bits(v.y); o.z = f2h_bits(v.z); o.w = f2h_bits(v.w);
    reinterpret_cast<u16x4*>(xh)[i] = o;
}

// ---------- W [K][N] fp32 -> WT [N][K] fp16 (transpose via LDS) ----------
__global__ __launch_bounds__(256) void k_cvt_wT(const float* __restrict__ W, u16* __restrict__ WT,
                                                int K, int N){
    __shared__ float t[32][33];
    int tx = threadIdx.x & 31, ty = threadIdx.x >> 5;   // 32 x 8
    int n0 = blockIdx.x*32, k0 = blockIdx.y*32;
    #pragma unroll
    for (int i=0;i<4;++i) t[ty+8*i][tx] = W[(size_t)(k0+ty+8*i)*N + n0+tx];
    __syncthreads();
    #pragma unroll
    for (int i=0;i<4;++i) WT[(size_t)(n0+ty+8*i)*K + k0+tx] = f2h_bits(t[tx][ty+8*i]);
}

// ---------- GEMM: C[M,N] = A[M,1024] * BT[N,1024]^T, fp16 in / fp32 acc ----------
template<int EPI>
__global__ __launch_bounds__(256) void k_gemm(const u16* __restrict__ A, const u16* __restrict__ BT,
                                              float* __restrict__ Cf, u16* __restrict__ Qh,
                                              u16* __restrict__ Kh, u16* __restrict__ Vt){
    constexpr int Kd = 1024;
    int w    = threadIdx.x >> 6;
    int lane = threadIdx.x & 63;
    int lr = lane & 15, lg = lane >> 4;
    int m0 = blockIdx.y*128 + (w>>1)*64;
    int n0 = blockIdx.x*128 + (w&1)*64;
    const u16* Ab = A  + (size_t)(m0+lr)*Kd + lg*8;
    const u16* Bb = BT + (size_t)(n0+lr)*Kd + lg*8;
    f32x4 acc[4][4];
    #pragma unroll
    for (int i=0;i<4;++i)
        #pragma unroll
        for (int j=0;j<4;++j) acc[i][j] = (f32x4){0.f,0.f,0.f,0.f};

    for (int kk=0; kk<Kd; kk+=32){
        half8 av[4], bv[4];
        #pragma unroll
        for (int mf=0;mf<4;++mf) av[mf] = *reinterpret_cast<const half8*>(Ab + (size_t)mf*16*Kd + kk);
        #pragma unroll
        for (int nf=0;nf<4;++nf) bv[nf] = *reinterpret_cast<const half8*>(Bb + (size_t)nf*16*Kd + kk);
        #pragma unroll
        for (int mf=0;mf<4;++mf)
            #pragma unroll
            for (int nf=0;nf<4;++nf)
                acc[mf][nf] = __builtin_amdgcn_mfma_f32_16x16x32_f16(av[mf], bv[nf], acc[mf][nf], 0,0,0);
    }

    if (EPI == 0){
        #pragma unroll
        for (int mf=0;mf<4;++mf)
            #pragma unroll
            for (int nf=0;nf<4;++nf)
                #pragma unroll
                for (int j=0;j<4;++j)
                    Cf[(size_t)(m0+mf*16+lg*4+j)*D_MODEL + n0+nf*16+lr] = acc[mf][nf][j];
    } else {
        #pragma unroll
        for (int mf=0;mf<4;++mf){
            int r0 = m0 + mf*16 + lg*4;
            int b  = r0 >> 11, s = r0 & 2047;
            #pragma unroll
            for (int nf=0;nf<4;++nf){
                int col = n0 + nf*16 + lr;
                int which = col >> 10;
                int d  = col & 1023;
                int h  = d >> 6, di = d & 63;
                int bh = b*NHEAD + h;
                if (which == 2){
                    u16x4 pv;
                    pv.x = f2h_bits(acc[mf][nf][0]);
                    pv.y = f2h_bits(acc[mf][nf][1]);
                    pv.z = f2h_bits(acc[mf][nf][2]);
                    pv.w = f2h_bits(acc[mf][nf][3]);
                    *reinterpret_cast<u16x4*>(Vt + ((size_t)bh*HDIM + di)*S_LEN + s) = pv;
                } else {
                    u16* dst = (which==0 ? Qh : Kh) + ((size_t)bh*S_LEN + s)*HDIM + di;
                    #pragma unroll
                    for (int j=0;j<4;++j) dst[(size_t)j*HDIM] = f2h_bits(acc[mf][nf][j]);
                }
            }
        }
    }
}

// ---------- flash attention v2 ----------
// 256 threads = 4 independent waves; each wave owns one 32-row q-tile; KVBLK=64.
// grid: blk = qgi*32 + bh  (bh in low 5 bits -> XCD = bh%8, clusters K/V in L2).
// qg = 15-qgi: heavy q-groups first (kills causal-triangle tail).
// exp2-domain softmax (Q pre-scaled by log2e), defer-rescale THR=8.
__global__ __launch_bounds__(256) void k_attn(const u16* __restrict__ Q, const u16* __restrict__ K,
                                              const u16* __restrict__ Vt, u16* __restrict__ Mg){
    __shared__ u16 plds[4][32][72];              // per-wave P tile, +8 pad
    int tid  = threadIdx.x;
    int w    = tid >> 6;
    int lane = tid & 63;
    int lr = lane & 15, lg = lane >> 4;
    int blk = blockIdx.x;
    int bh  = blk & 31;
    int qgi = blk >> 5;                          // 0..15
    int qt  = (15 - qgi)*4 + w;                  // q-tile 0..63, heavy first
    int q0  = qt*32;
    int b = bh >> 4, h = bh & 15;
    const u16* Qp = Q  + (size_t)bh*S_LEN*HDIM;
    const u16* Kp = K  + (size_t)bh*S_LEN*HDIM;
    const u16* Vp = Vt + (size_t)bh*HDIM*S_LEN;

    // Q fragments, pre-scaled by log2(e) -> softmax in exp2 domain
    half8 qf[2][2];
    #pragma unroll
    for (int mf=0;mf<2;++mf)
        #pragma unroll
        for (int ks=0;ks<2;++ks){
            half8 v = *reinterpret_cast<const half8*>(Qp + (size_t)(q0+mf*16+lr)*HDIM + ks*32 + lg*8);
            #pragma unroll
            for (int j=0;j<8;++j) v[j] = v[j] * (_Float16)1.44269504f;
            qf[mf][ks] = v;
        }

    f32x4 oacc[2][4];
    float mrow[2][4], lrow[2][4];
    #pragma unroll
    for (int mf=0;mf<2;++mf){
        #pragma unroll
        for (int nf=0;nf<4;++nf) oacc[mf][nf] = (f32x4){0.f,0.f,0.f,0.f};
        #pragma unroll
        for (int j=0;j<4;++j){ mrow[mf][j] = -1e30f; lrow[mf][j] = 0.f; }
    }

    int ktiles = (q0 + 32 + 63) >> 6;            // 64-wide k tiles covering [0, q0+32)
    for (int kt=0; kt<ktiles; ++kt){
        int kbase = kt*64;
        // --- QK^T (scores already in log2 domain via scaled Q) ---
        half8 kf[4][2];
        #pragma unroll
        for (int nf=0;nf<4;++nf)
            #pragma unroll
            for (int ks=0;ks<2;++ks)
                kf[nf][ks] = *reinterpret_cast<const half8*>(Kp + (size_t)(kbase+nf*16+lr)*HDIM + ks*32 + lg*8);
        f32x4 sc[2][4];
        #pragma unroll
        for (int mf=0;mf<2;++mf)
            #pragma unroll
            for (int nf=0;nf<4;++nf) sc[mf][nf] = (f32x4){0.f,0.f,0.f,0.f};
        #pragma unroll
        for (int mf=0;mf<2;++mf)
            #pragma unroll
            for (int nf=0;nf<4;++nf)
                #pragma unroll
                for (int ks=0;ks<2;++ks)
                    sc[mf][nf] = __builtin_amdgcn_mfma_f32_16x16x32_f16(qf[mf][ks], kf[nf][ks], sc[mf][nf], 0,0,0);

        if (kt == ktiles-1){                     // tail tile: causal mask
            #pragma unroll
            for (int mf=0;mf<2;++mf)
                #pragma unroll
                for (int nf=0;nf<4;++nf)
                    #pragma unroll
                    for (int j=0;j<4;++j)
                        if (kbase+nf*16+lr > q0+mf*16+lg*4+j) sc[mf][nf][j] = -1e9f;
        }

        // --- V loads issued early: VMEM latency hides under softmax VALU ---
        half8 vf[4][2];
        #pragma unroll
        for (int nf=0;nf<4;++nf)
            #pragma unroll
            for (int kh=0;kh<2;++kh)
                vf[nf][kh] = *reinterpret_cast<const half8*>(Vp + (size_t)(nf*16+lr)*S_LEN + kbase + kh*32 + lg*8);

        // --- row max (this tile) ---
        float pmax[2][4];
        #pragma unroll
        for (int mf=0;mf<2;++mf)
            #pragma unroll
            for (int j=0;j<4;++j){
                float t = fmaxf(fmaxf(sc[mf][0][j], sc[mf][1][j]), fmaxf(sc[mf][2][j], sc[mf][3][j]));
                t = fmaxf(t, __shfl_xor(t,1));
                t = fmaxf(t, __shfl_xor(t,2));
                t = fmaxf(t, __shfl_xor(t,4));
                t = fmaxf(t, __shfl_xor(t,8));
                pmax[mf][j] = t;
            }
        // --- defer-rescale (T13, THR=8 in log2 domain -> P <= 2^8) ---
        bool need = false;
        #pragma unroll
        for (int mf=0;mf<2;++mf)
            #pragma unroll
            for (int j=0;j<4;++j) need |= (pmax[mf][j] > mrow[mf][j] + 8.0f);
        if (__any(need)){
            #pragma unroll
            for (int mf=0;mf<2;++mf)
                #pragma unroll
                for (int j=0;j<4;++j){
                    float mnew = fmaxf(mrow[mf][j], pmax[mf][j]);
                    float a = __builtin_amdgcn_exp2f(mrow[mf][j] - mnew);
                    mrow[mf][j] = mnew;
                    lrow[mf][j] *= a;
                    #pragma unroll
                    for (int nf=0;nf<4;++nf) oacc[mf][nf][j] *= a;
                }
        }
        // --- P = exp2(s - m), row sum ---
        #pragma unroll
        for (int mf=0;mf<2;++mf)
            #pragma unroll
            for (int j=0;j<4;++j){
                float m = mrow[mf][j];
                float e0 = __builtin_amdgcn_exp2f(sc[mf][0][j] - m);
                float e1 = __builtin_amdgcn_exp2f(sc[mf][1][j] - m);
                float e2 = __builtin_amdgcn_exp2f(sc[mf][2][j] - m);
                float e3 = __builtin_amdgcn_exp2f(sc[mf][3][j] - m);
                sc[mf][0][j]=e0; sc[mf][1][j]=e1; sc[mf][2][j]=e2; sc[mf][3][j]=e3;
                float rs = (e0+e1)+(e2+e3);
                rs += __shfl_xor(rs,1);
                rs += __shfl_xor(rs,2);
                rs += __shfl_xor(rs,4);
                rs += __shfl_xor(rs,8);
                lrow[mf][j] += rs;
            }
        // --- P -> LDS (D-layout -> A-layout transpose), intra-wave ---
        #pragma unroll
        for (int mf=0;mf<2;++mf)
            #pragma unroll
            for (int nf=0;nf<4;++nf)
                #pragma unroll
                for (int j=0;j<4;++j)
                    plds[w][mf*16+lg*4+j][nf*16+lr] = f2h_bits(sc[mf][nf][j]);
        asm volatile("s_waitcnt lgkmcnt(0)" ::: "memory");
        __builtin_amdgcn_sched_barrier(0);

        half8 pa[2][2];
        #pragma unroll
        for (int mf=0;mf<2;++mf)
            #pragma unroll
            for (int kh=0;kh<2;++kh)
                pa[mf][kh] = *reinterpret_cast<const half8*>(&plds[w][mf*16+lr][kh*32 + lg*8]);
        #pragma unroll
        for (int mf=0;mf<2;++mf)
            #pragma unroll
            for (int nf=0;nf<4;++nf)
                #pragma unroll
                for (int kh=0;kh<2;++kh)
                    oacc[mf][nf] = __builtin_amdgcn_mfma_f32_16x16x32_f16(pa[mf][kh], vf[nf][kh], oacc[mf][nf], 0,0,0);
    }

    float invl[2][4];
    #pragma unroll
    for (int mf=0;mf<2;++mf)
        #pragma unroll
        for (int j=0;j<4;++j) invl[mf][j] = 1.0f/lrow[mf][j];
    #pragma unroll
    for (int mf=0;mf<2;++mf)
        #pragma unroll
        for (int nf=0;nf<4;++nf)
            #pragma unroll
            for (int j=0;j<4;++j)
                Mg[(size_t)(b*S_LEN + q0 + mf*16 + lg*4 + j)*D_MODEL + h*HDIM + nf*16 + lr]
                    = f2h_bits(oacc[mf][nf][j]*invl[mf][j]);
}

extern "C" void kernel_launch(void* const* d_in, const int* in_sizes, int n_in,
                              void* d_out, int out_size, void* d_ws, size_t ws_size,
                              hipStream_t stream) {
    const float* x    = (const float*)d_in[0];
    const float* wqkv = (const float*)d_in[1];
    const float* wout = (const float*)d_in[2];
    float* out = (float*)d_out;
    char* ws = (char*)d_ws;

    const size_t MB = 1u<<20;
    u16* xh     = (u16*)(ws + 0*MB);
    u16* wqkvT  = (u16*)(ws + 8*MB);
    u16* woutT  = (u16*)(ws + 14*MB);
    u16* Qh     = (u16*)(ws + 16*MB);
    u16* Kh     = (u16*)(ws + 24*MB);
    u16* Vt     = (u16*)(ws + 32*MB);
    u16* Mg     = (u16*)(ws + 40*MB);

    k_cvt_x <<<4096, 256, 0, stream>>>(x, xh);
    k_cvt_wT<<<dim3(96,32), 256, 0, stream>>>(wqkv, wqkvT, 1024, 3072);
    k_cvt_wT<<<dim3(32,32), 256, 0, stream>>>(wout, woutT, 1024, 1024);
    k_gemm<1><<<dim3(24,32), 256, 0, stream>>>(xh, wqkvT, nullptr, Qh, Kh, Vt);
    k_attn  <<<512, 256, 0, stream>>>(Qh, Kh, Vt, Mg);
    k_gemm<0><<<dim3(8,32), 256, 0, stream>>>(Mg, woutT, out, nullptr, nullptr, nullptr);
}

// Round 3
// 214.622 us; speedup vs baseline: 1.4298x; 1.1323x over previous
//
#include <hip/hip_runtime.h>

using u16 = unsigned short;
typedef __attribute__((ext_vector_type(8))) _Float16 half8;
typedef __attribute__((ext_vector_type(4))) float f32x4;
typedef __attribute__((ext_vector_type(4))) unsigned short u16x4;

#define S_LEN 2048
#define D_MODEL 1024
#define NHEAD 16
#define HDIM 64

__device__ __forceinline__ u16 f2h_bits(float f){
    _Float16 h = (_Float16)f;
    return __builtin_bit_cast(u16, h);
}

// ---------- x fp32 -> fp16 ----------
__global__ __launch_bounds__(256) void k_cvt_x(const float* __restrict__ x, u16* __restrict__ xh){
    int i = blockIdx.x*256 + threadIdx.x;
    float4 v = reinterpret_cast<const float4*>(x)[i];
    u16x4 o;
    o.x = f2h_bits(v.x); o.y = f2h_bits(v.y); o.z = f2h_bits(v.z); o.w = f2h_bits(v.w);
    reinterpret_cast<u16x4*>(xh)[i] = o;
}

// ---------- W [K][N] fp32 -> WT [N][K] fp16 (transpose via LDS) ----------
__global__ __launch_bounds__(256) void k_cvt_wT(const float* __restrict__ W, u16* __restrict__ WT,
                                                int K, int N){
    __shared__ float t[32][33];
    int tx = threadIdx.x & 31, ty = threadIdx.x >> 5;   // 32 x 8
    int n0 = blockIdx.x*32, k0 = blockIdx.y*32;
    #pragma unroll
    for (int i=0;i<4;++i) t[ty+8*i][tx] = W[(size_t)(k0+ty+8*i)*N + n0+tx];
    __syncthreads();
    #pragma unroll
    for (int i=0;i<4;++i) WT[(size_t)(n0+ty+8*i)*K + k0+tx] = f2h_bits(t[tx][ty+8*i]);
}

// ---------- GEMM: C[M,N] = A[M,1024] * BT[N,1024]^T, fp16 in / fp32 acc ----------
template<int EPI>
__global__ __launch_bounds__(256) void k_gemm(const u16* __restrict__ A, const u16* __restrict__ BT,
                                              float* __restrict__ Cf, u16* __restrict__ Qh,
                                              u16* __restrict__ Kh, u16* __restrict__ Vt){
    constexpr int Kd = 1024;
    int w    = threadIdx.x >> 6;
    int lane = threadIdx.x & 63;
    int lr = lane & 15, lg = lane >> 4;
    int m0 = blockIdx.y*128 + (w>>1)*64;
    int n0 = blockIdx.x*128 + (w&1)*64;
    const u16* Ab = A  + (size_t)(m0+lr)*Kd + lg*8;
    const u16* Bb = BT + (size_t)(n0+lr)*Kd + lg*8;
    f32x4 acc[4][4];
    #pragma unroll
    for (int i=0;i<4;++i)
        #pragma unroll
        for (int j=0;j<4;++j) acc[i][j] = (f32x4){0.f,0.f,0.f,0.f};

    for (int kk=0; kk<Kd; kk+=32){
        half8 av[4], bv[4];
        #pragma unroll
        for (int mf=0;mf<4;++mf) av[mf] = *reinterpret_cast<const half8*>(Ab + (size_t)mf*16*Kd + kk);
        #pragma unroll
        for (int nf=0;nf<4;++nf) bv[nf] = *reinterpret_cast<const half8*>(Bb + (size_t)nf*16*Kd + kk);
        #pragma unroll
        for (int mf=0;mf<4;++mf)
            #pragma unroll
            for (int nf=0;nf<4;++nf)
                acc[mf][nf] = __builtin_amdgcn_mfma_f32_16x16x32_f16(av[mf], bv[nf], acc[mf][nf], 0,0,0);
    }

    if (EPI == 0){
        #pragma unroll
        for (int mf=0;mf<4;++mf)
            #pragma unroll
            for (int nf=0;nf<4;++nf)
                #pragma unroll
                for (int j=0;j<4;++j)
                    Cf[(size_t)(m0+mf*16+lg*4+j)*D_MODEL + n0+nf*16+lr] = acc[mf][nf][j];
    } else {
        #pragma unroll
        for (int mf=0;mf<4;++mf){
            int r0 = m0 + mf*16 + lg*4;
            int b  = r0 >> 11, s = r0 & 2047;
            #pragma unroll
            for (int nf=0;nf<4;++nf){
                int col = n0 + nf*16 + lr;
                int which = col >> 10;
                int d  = col & 1023;
                int h  = d >> 6, di = d & 63;
                int bh = b*NHEAD + h;
                if (which == 2){
                    u16x4 pv;
                    pv.x = f2h_bits(acc[mf][nf][0]);
                    pv.y = f2h_bits(acc[mf][nf][1]);
                    pv.z = f2h_bits(acc[mf][nf][2]);
                    pv.w = f2h_bits(acc[mf][nf][3]);
                    *reinterpret_cast<u16x4*>(Vt + ((size_t)bh*HDIM + di)*S_LEN + s) = pv;
                } else {
                    u16* dst = (which==0 ? Qh : Kh) + ((size_t)bh*S_LEN + s)*HDIM + di;
                    #pragma unroll
                    for (int j=0;j<4;++j) dst[(size_t)j*HDIM] = f2h_bits(acc[mf][nf][j]);
                }
            }
        }
    }
}

// ---------- flash attention v3 ----------
// 1 wave per block (2048 blocks), heavy q-tiles first (dynamic CU balance).
// bh = blk&31 -> XCD = blk%8 fixed per bh group (K/V L2-resident per XCD).
// Swapped QK^T: sc_T = mfma(K, Q) so each lane owns full k-slices of ONE q-row:
//   row max / sum = in-register over 16 + 2 shuffles (vs 4+4 shfl per row before).
//   P j-regs are k-contiguous -> pack u16x4, 8x ds_write_b64 (vs 32x ds_write_b16).
// exp2-domain softmax (Q pre-scaled by log2e), defer-rescale THR=8 (P <= 256, fp16-safe).
__global__ __launch_bounds__(64,3) void k_attn(const u16* __restrict__ Q, const u16* __restrict__ K,
                                               const u16* __restrict__ Vt, u16* __restrict__ Mg){
    __shared__ u16 plds[32][72];                 // 144B rows: 16B-aligned b128 reads
    int lane = threadIdx.x;
    int lr = lane & 15, lg = lane >> 4;
    int blk = blockIdx.x;
    int bh  = blk & 31;
    int qt  = 63 - (blk >> 5);                   // heavy first
    int q0  = qt*32;
    int b = bh >> 4, h = bh & 15;
    const u16* Qp = Q  + (size_t)bh*S_LEN*HDIM;
    const u16* Kp = K  + (size_t)bh*S_LEN*HDIM;
    const u16* Vp = Vt + (size_t)bh*HDIM*S_LEN;

    // Q fragments (B-operand), pre-scaled by log2(e)
    half8 qf[2][2];
    #pragma unroll
    for (int qi=0;qi<2;++qi)
        #pragma unroll
        for (int ks=0;ks<2;++ks){
            half8 v = *reinterpret_cast<const half8*>(Qp + (size_t)(q0+qi*16+lr)*HDIM + ks*32 + lg*8);
            #pragma unroll
            for (int j=0;j<8;++j) v[j] = v[j] * (_Float16)1.44269504f;
            qf[qi][ks] = v;
        }

    f32x4 oacc[2][4];                            // [q-frag][d-frag], row q = mf*16+lg*4+j
    float mrow[2], lrow[2];                      // per q-frag, q = qf*16+lr (lane-local)
    #pragma unroll
    for (int mf=0;mf<2;++mf){
        #pragma unroll
        for (int nf=0;nf<4;++nf) oacc[mf][nf] = (f32x4){0.f,0.f,0.f,0.f};
        mrow[mf] = -1e30f; lrow[mf] = 0.f;
    }

    int ktiles = (q0 + 32 + 63) >> 6;
    for (int kt=0; kt<ktiles; ++kt){
        int kbase = kt*64;
        // --- K fragments (A-operand) ---
        half8 kfr[4][2];
        #pragma unroll
        for (int kf=0;kf<4;++kf)
            #pragma unroll
            for (int ks=0;ks<2;++ks)
                kfr[kf][ks] = *reinterpret_cast<const half8*>(Kp + (size_t)(kbase+kf*16+lr)*HDIM + ks*32 + lg*8);
        // --- S^T = K Q^T : lane holds k = kf*16+lg*4+j, q = qi*16+lr ---
        f32x4 sc[4][2];
        #pragma unroll
        for (int kf=0;kf<4;++kf)
            #pragma unroll
            for (int qi=0;qi<2;++qi) sc[kf][qi] = (f32x4){0.f,0.f,0.f,0.f};
        __builtin_amdgcn_s_setprio(1);
        #pragma unroll
        for (int kf=0;kf<4;++kf)
            #pragma unroll
            for (int qi=0;qi<2;++qi)
                #pragma unroll
                for (int ks=0;ks<2;++ks)
                    sc[kf][qi] = __builtin_amdgcn_mfma_f32_16x16x32_f16(kfr[kf][ks], qf[qi][ks], sc[kf][qi], 0,0,0);
        __builtin_amdgcn_s_setprio(0);

        // --- V loads issued early: latency hides under softmax ---
        half8 vf[4][2];
        #pragma unroll
        for (int nf=0;nf<4;++nf)
            #pragma unroll
            for (int kh=0;kh<2;++kh)
                vf[nf][kh] = *reinterpret_cast<const half8*>(Vp + (size_t)(nf*16+lr)*S_LEN + kbase + kh*32 + lg*8);

        if (kt == ktiles-1){                     // causal mask on tail tile
            #pragma unroll
            for (int kf=0;kf<4;++kf)
                #pragma unroll
                for (int qi=0;qi<2;++qi)
                    #pragma unroll
                    for (int j=0;j<4;++j)
                        if (kbase+kf*16+lg*4+j > q0+qi*16+lr) sc[kf][qi][j] = -1e9f;
        }

        // --- row max: 16 in-reg + 2 shuffles per q-frag ---
        float pmax[2];
        #pragma unroll
        for (int qi=0;qi<2;++qi){
            float t0 = fmaxf(fmaxf(sc[0][qi][0], sc[0][qi][1]), fmaxf(sc[0][qi][2], sc[0][qi][3]));
            float t1 = fmaxf(fmaxf(sc[1][qi][0], sc[1][qi][1]), fmaxf(sc[1][qi][2], sc[1][qi][3]));
            float t2 = fmaxf(fmaxf(sc[2][qi][0], sc[2][qi][1]), fmaxf(sc[2][qi][2], sc[2][qi][3]));
            float t3 = fmaxf(fmaxf(sc[3][qi][0], sc[3][qi][1]), fmaxf(sc[3][qi][2], sc[3][qi][3]));
            float t = fmaxf(fmaxf(t0,t1), fmaxf(t2,t3));
            t = fmaxf(t, __shfl_xor(t,16));
            t = fmaxf(t, __shfl_xor(t,32));
            pmax[qi] = t;
        }
        // --- defer-rescale (THR=8 in log2 domain) ---
        bool need = (pmax[0] > mrow[0]+8.0f) || (pmax[1] > mrow[1]+8.0f);
        if (__any(need)){
            float aq[2];
            #pragma unroll
            for (int qi=0;qi<2;++qi){
                float mnew = fmaxf(mrow[qi], pmax[qi]);
                aq[qi] = __builtin_amdgcn_exp2f(mrow[qi] - mnew);
                mrow[qi] = mnew;
                lrow[qi] *= aq[qi];
            }
            float am[2][4];
            #pragma unroll
            for (int mf=0;mf<2;++mf)
                #pragma unroll
                for (int j=0;j<4;++j) am[mf][j] = __shfl(aq[mf], lg*4+j);
            #pragma unroll
            for (int mf=0;mf<2;++mf)
                #pragma unroll
                for (int nf=0;nf<4;++nf)
                    #pragma unroll
                    for (int j=0;j<4;++j) oacc[mf][nf][j] *= am[mf][j];
        }
        // --- P = exp2(s - m), row sum in-register ---
        #pragma unroll
        for (int qi=0;qi<2;++qi){
            float m = mrow[qi];
            float rs = 0.f;
            #pragma unroll
            for (int kf=0;kf<4;++kf){
                #pragma unroll
                for (int j=0;j<4;++j){
                    float e = __builtin_amdgcn_exp2f(sc[kf][qi][j] - m);
                    sc[kf][qi][j] = e;
                    rs += e;
                }
            }
            rs += __shfl_xor(rs,16);
            rs += __shfl_xor(rs,32);
            lrow[qi] += rs;
        }
        // --- P -> LDS: k-contiguous j-regs pack to u16x4, 8x ds_write_b64 ---
        #pragma unroll
        for (int kf=0;kf<4;++kf)
            #pragma unroll
            for (int qi=0;qi<2;++qi){
                u16x4 pk;
                pk.x = f2h_bits(sc[kf][qi][0]);
                pk.y = f2h_bits(sc[kf][qi][1]);
                pk.z = f2h_bits(sc[kf][qi][2]);
                pk.w = f2h_bits(sc[kf][qi][3]);
                *reinterpret_cast<u16x4*>(&plds[qi*16+lr][kf*16+lg*4]) = pk;
            }
        asm volatile("s_waitcnt lgkmcnt(0)" ::: "memory");
        __builtin_amdgcn_sched_barrier(0);

        half8 pa[2][2];
        #pragma unroll
        for (int mf=0;mf<2;++mf)
            #pragma unroll
            for (int kh=0;kh<2;++kh)
                pa[mf][kh] = *reinterpret_cast<const half8*>(&plds[mf*16+lr][kh*32 + lg*8]);
        __builtin_amdgcn_s_setprio(1);
        #pragma unroll
        for (int mf=0;mf<2;++mf)
            #pragma unroll
            for (int nf=0;nf<4;++nf)
                #pragma unroll
                for (int kh=0;kh<2;++kh)
                    oacc[mf][nf] = __builtin_amdgcn_mfma_f32_16x16x32_f16(pa[mf][kh], vf[nf][kh], oacc[mf][nf], 0,0,0);
        __builtin_amdgcn_s_setprio(0);
    }

    // epilogue: redistribute 1/l to oacc row layout (8 shuffles once)
    float linv[2][4];
    #pragma unroll
    for (int mf=0;mf<2;++mf)
        #pragma unroll
        for (int j=0;j<4;++j) linv[mf][j] = 1.0f/__shfl(lrow[mf], lg*4+j);
    #pragma unroll
    for (int mf=0;mf<2;++mf)
        #pragma unroll
        for (int nf=0;nf<4;++nf)
            #pragma unroll
            for (int j=0;j<4;++j)
                Mg[(size_t)(b*S_LEN + q0 + mf*16 + lg*4 + j)*D_MODEL + h*HDIM + nf*16 + lr]
                    = f2h_bits(oacc[mf][nf][j]*linv[mf][j]);
}

extern "C" void kernel_launch(void* const* d_in, const int* in_sizes, int n_in,
                              void* d_out, int out_size, void* d_ws, size_t ws_size,
                              hipStream_t stream) {
    const float* x    = (const float*)d_in[0];
    const float* wqkv = (const float*)d_in[1];
    const float* wout = (const float*)d_in[2];
    float* out = (float*)d_out;
    char* ws = (char*)d_ws;

    const size_t MB = 1u<<20;
    u16* xh     = (u16*)(ws + 0*MB);
    u16* wqkvT  = (u16*)(ws + 8*MB);
    u16* woutT  = (u16*)(ws + 14*MB);
    u16* Qh     = (u16*)(ws + 16*MB);
    u16* Kh     = (u16*)(ws + 24*MB);
    u16* Vt     = (u16*)(ws + 32*MB);
    u16* Mg     = (u16*)(ws + 40*MB);

    k_cvt_x <<<4096, 256, 0, stream>>>(x, xh);
    k_cvt_wT<<<dim3(96,32), 256, 0, stream>>>(wqkv, wqkvT, 1024, 3072);
    k_cvt_wT<<<dim3(32,32), 256, 0, stream>>>(wout, woutT, 1024, 1024);
    k_gemm<1><<<dim3(24,32), 256, 0, stream>>>(xh, wqkvT, nullptr, Qh, Kh, Vt);
    k_attn  <<<2048, 64, 0, stream>>>(Qh, Kh, Vt, Mg);
    k_gemm<0><<<dim3(8,32), 256, 0, stream>>>(Mg, woutT, out, nullptr, nullptr, nullptr);
}

// Round 4
// 152.938 us; speedup vs baseline: 2.0065x; 1.4033x over previous
//
#include <hip/hip_runtime.h>
#include <stdint.h>

using u16 = unsigned short;
typedef __attribute__((ext_vector_type(8))) _Float16 half8;
typedef __attribute__((ext_vector_type(4))) float f32x4;
typedef __attribute__((ext_vector_type(4))) unsigned short u16x4;

#define S_LEN 2048
#define D_MODEL 1024
#define NHEAD 16
#define HDIM 64

__device__ __forceinline__ u16 f2h_bits(float f){
    _Float16 h = (_Float16)f;
    return __builtin_bit_cast(u16, h);
}

typedef __attribute__((address_space(1))) void gvoid;
typedef __attribute__((address_space(3))) void lvoid;
__device__ __forceinline__ void gload_lds16(const u16* g, u16* l){
    __builtin_amdgcn_global_load_lds((gvoid*)(uintptr_t)g, (lvoid*)l, 16, 0, 0);
}

// ---------- x fp32 -> fp16 ----------
__global__ __launch_bounds__(256) void k_cvt_x(const float* __restrict__ x, u16* __restrict__ xh){
    int i = blockIdx.x*256 + threadIdx.x;
    float4 v = reinterpret_cast<const float4*>(x)[i];
    u16x4 o;
    o.x = f2h_bits(v.x); o.y = f2h_bits(v.y); o.z = f2h_bits(v.z); o.w = f2h_bits(v.w);
    reinterpret_cast<u16x4*>(xh)[i] = o;
}

// ---------- W [K][N] fp32 -> WT [N][K] fp16 (transpose via LDS) ----------
__global__ __launch_bounds__(256) void k_cvt_wT(const float* __restrict__ W, u16* __restrict__ WT,
                                                int K, int N){
    __shared__ float t[32][33];
    int tx = threadIdx.x & 31, ty = threadIdx.x >> 5;   // 32 x 8
    int n0 = blockIdx.x*32, k0 = blockIdx.y*32;
    #pragma unroll
    for (int i=0;i<4;++i) t[ty+8*i][tx] = W[(size_t)(k0+ty+8*i)*N + n0+tx];
    __syncthreads();
    #pragma unroll
    for (int i=0;i<4;++i) WT[(size_t)(n0+ty+8*i)*K + k0+tx] = f2h_bits(t[tx][ty+8*i]);
}

// ---------- GEMM v2 (m97 structure): 128x128 tile, BK=32, LDS-staged via global_load_lds ----------
// C[M,N] = A[M,1024] * BT[N,1024]^T, fp16 in / fp32 acc.
// Grid is 1D (Mtiles=32 fixed); bijective XCD swizzle (nwg % 8 == 0).
// EPI 0: write fp32 C.  EPI 1: scatter QKV (Q,K row-major per head; V transposed).
template<int EPI>
__global__ __launch_bounds__(256) void k_gemm(const u16* __restrict__ A, const u16* __restrict__ BT,
                                              float* __restrict__ Cf, u16* __restrict__ Qh,
                                              u16* __restrict__ Kh, u16* __restrict__ Vt){
    constexpr int Kd = 1024;
    __shared__ u16 As[128*32];
    __shared__ u16 Bs[128*32];
    int nwg = gridDim.x;
    int cpx = nwg >> 3;
    int wg  = ((int)blockIdx.x & 7)*cpx + ((int)blockIdx.x >> 3);   // XCD-chunked
    int tm = wg & 31, tn = wg >> 5;                                 // m-fastest within chunk
    int t = threadIdx.x;
    int w = t >> 6, lane = t & 63;
    int lr = lane & 15, lg = lane >> 4;
    int wm = (w>>1)*64, wn = (w&1)*64;
    int m0 = tm*128 + wm, n0 = tn*128 + wn;

    // staging addresses: thread t covers row (t>>2), 16B chunk (t&3) of a 64-row half-tile
    const u16* aG = A  + (size_t)(tm*128 + (t>>2))*Kd + (t&3)*8;
    const u16* bG = BT + (size_t)(tn*128 + (t>>2))*Kd + (t&3)*8;
    u16* aL = As + (t>>2)*32 + (t&3)*8;
    u16* bL = Bs + (t>>2)*32 + (t&3)*8;

    f32x4 acc[4][4];
    #pragma unroll
    for (int i=0;i<4;++i)
        #pragma unroll
        for (int j=0;j<4;++j) acc[i][j] = (f32x4){0.f,0.f,0.f,0.f};

    for (int kk=0; kk<Kd; kk+=32){
        gload_lds16(aG + kk, aL);
        gload_lds16(aG + kk + (size_t)64*Kd, aL + 64*32);
        gload_lds16(bG + kk, bL);
        gload_lds16(bG + kk + (size_t)64*Kd, bL + 64*32);
        __syncthreads();                       // compiler drains vmcnt before barrier

        half8 av[4], bv[4];
        #pragma unroll
        for (int mf=0;mf<4;++mf) av[mf] = *reinterpret_cast<const half8*>(&As[(wm+mf*16+lr)*32 + lg*8]);
        #pragma unroll
        for (int nf=0;nf<4;++nf) bv[nf] = *reinterpret_cast<const half8*>(&Bs[(wn+nf*16+lr)*32 + lg*8]);
        __builtin_amdgcn_s_setprio(1);
        #pragma unroll
        for (int mf=0;mf<4;++mf)
            #pragma unroll
            for (int nf=0;nf<4;++nf)
                acc[mf][nf] = __builtin_amdgcn_mfma_f32_16x16x32_f16(av[mf], bv[nf], acc[mf][nf], 0,0,0);
        __builtin_amdgcn_s_setprio(0);
        __syncthreads();                       // protect LDS before next-stage overwrite
    }

    if (EPI == 0){
        #pragma unroll
        for (int mf=0;mf<4;++mf)
            #pragma unroll
            for (int nf=0;nf<4;++nf)
                #pragma unroll
                for (int j=0;j<4;++j)
                    Cf[(size_t)(m0+mf*16+lg*4+j)*D_MODEL + n0+nf*16+lr] = acc[mf][nf][j];
    } else {
        #pragma unroll
        for (int mf=0;mf<4;++mf){
            int r0 = m0 + mf*16 + lg*4;
            int b  = r0 >> 11, s = r0 & 2047;
            #pragma unroll
            for (int nf=0;nf<4;++nf){
                int col = n0 + nf*16 + lr;
                int which = col >> 10;
                int d  = col & 1023;
                int h  = d >> 6, di = d & 63;
                int bh = b*NHEAD + h;
                if (which == 2){
                    u16x4 pv;
                    pv.x = f2h_bits(acc[mf][nf][0]);
                    pv.y = f2h_bits(acc[mf][nf][1]);
                    pv.z = f2h_bits(acc[mf][nf][2]);
                    pv.w = f2h_bits(acc[mf][nf][3]);
                    *reinterpret_cast<u16x4*>(Vt + ((size_t)bh*HDIM + di)*S_LEN + s) = pv;
                } else {
                    u16* dst = (which==0 ? Qh : Kh) + ((size_t)bh*S_LEN + s)*HDIM + di;
                    #pragma unroll
                    for (int j=0;j<4;++j) dst[(size_t)j*HDIM] = f2h_bits(acc[mf][nf][j]);
                }
            }
        }
    }
}

// ---------- flash attention v3 (unchanged from round 3) ----------
__global__ __launch_bounds__(64,3) void k_attn(const u16* __restrict__ Q, const u16* __restrict__ K,
                                               const u16* __restrict__ Vt, u16* __restrict__ Mg){
    __shared__ u16 plds[32][72];
    int lane = threadIdx.x;
    int lr = lane & 15, lg = lane >> 4;
    int blk = blockIdx.x;
    int bh  = blk & 31;
    int qt  = 63 - (blk >> 5);
    int q0  = qt*32;
    int b = bh >> 4, h = bh & 15;
    const u16* Qp = Q  + (size_t)bh*S_LEN*HDIM;
    const u16* Kp = K  + (size_t)bh*S_LEN*HDIM;
    const u16* Vp = Vt + (size_t)bh*HDIM*S_LEN;

    half8 qf[2][2];
    #pragma unroll
    for (int qi=0;qi<2;++qi)
        #pragma unroll
        for (int ks=0;ks<2;++ks){
            half8 v = *reinterpret_cast<const half8*>(Qp + (size_t)(q0+qi*16+lr)*HDIM + ks*32 + lg*8);
            #pragma unroll
            for (int j=0;j<8;++j) v[j] = v[j] * (_Float16)1.44269504f;
            qf[qi][ks] = v;
        }

    f32x4 oacc[2][4];
    float mrow[2], lrow[2];
    #pragma unroll
    for (int mf=0;mf<2;++mf){
        #pragma unroll
        for (int nf=0;nf<4;++nf) oacc[mf][nf] = (f32x4){0.f,0.f,0.f,0.f};
        mrow[mf] = -1e30f; lrow[mf] = 0.f;
    }

    int ktiles = (q0 + 32 + 63) >> 6;
    for (int kt=0; kt<ktiles; ++kt){
        int kbase = kt*64;
        half8 kfr[4][2];
        #pragma unroll
        for (int kf=0;kf<4;++kf)
            #pragma unroll
            for (int ks=0;ks<2;++ks)
                kfr[kf][ks] = *reinterpret_cast<const half8*>(Kp + (size_t)(kbase+kf*16+lr)*HDIM + ks*32 + lg*8);
        f32x4 sc[4][2];
        #pragma unroll
        for (int kf=0;kf<4;++kf)
            #pragma unroll
            for (int qi=0;qi<2;++qi) sc[kf][qi] = (f32x4){0.f,0.f,0.f,0.f};
        __builtin_amdgcn_s_setprio(1);
        #pragma unroll
        for (int kf=0;kf<4;++kf)
            #pragma unroll
            for (int qi=0;qi<2;++qi)
                #pragma unroll
                for (int ks=0;ks<2;++ks)
                    sc[kf][qi] = __builtin_amdgcn_mfma_f32_16x16x32_f16(kfr[kf][ks], qf[qi][ks], sc[kf][qi], 0,0,0);
        __builtin_amdgcn_s_setprio(0);

        half8 vf[4][2];
        #pragma unroll
        for (int nf=0;nf<4;++nf)
            #pragma unroll
            for (int kh=0;kh<2;++kh)
                vf[nf][kh] = *reinterpret_cast<const half8*>(Vp + (size_t)(nf*16+lr)*S_LEN + kbase + kh*32 + lg*8);

        if (kt == ktiles-1){
            #pragma unroll
            for (int kf=0;kf<4;++kf)
                #pragma unroll
                for (int qi=0;qi<2;++qi)
                    #pragma unroll
                    for (int j=0;j<4;++j)
                        if (kbase+kf*16+lg*4+j > q0+qi*16+lr) sc[kf][qi][j] = -1e9f;
        }

        float pmax[2];
        #pragma unroll
        for (int qi=0;qi<2;++qi){
            float t0 = fmaxf(fmaxf(sc[0][qi][0], sc[0][qi][1]), fmaxf(sc[0][qi][2], sc[0][qi][3]));
            float t1 = fmaxf(fmaxf(sc[1][qi][0], sc[1][qi][1]), fmaxf(sc[1][qi][2], sc[1][qi][3]));
            float t2 = fmaxf(fmaxf(sc[2][qi][0], sc[2][qi][1]), fmaxf(sc[2][qi][2], sc[2][qi][3]));
            float t3 = fmaxf(fmaxf(sc[3][qi][0], sc[3][qi][1]), fmaxf(sc[3][qi][2], sc[3][qi][3]));
            float t = fmaxf(fmaxf(t0,t1), fmaxf(t2,t3));
            t = fmaxf(t, __shfl_xor(t,16));
            t = fmaxf(t, __shfl_xor(t,32));
            pmax[qi] = t;
        }
        bool need = (pmax[0] > mrow[0]+8.0f) || (pmax[1] > mrow[1]+8.0f);
        if (__any(need)){
            float aq[2];
            #pragma unroll
            for (int qi=0;qi<2;++qi){
                float mnew = fmaxf(mrow[qi], pmax[qi]);
                aq[qi] = __builtin_amdgcn_exp2f(mrow[qi] - mnew);
                mrow[qi] = mnew;
                lrow[qi] *= aq[qi];
            }
            float am[2][4];
            #pragma unroll
            for (int mf=0;mf<2;++mf)
                #pragma unroll
                for (int j=0;j<4;++j) am[mf][j] = __shfl(aq[mf], lg*4+j);
            #pragma unroll
            for (int mf=0;mf<2;++mf)
                #pragma unroll
                for (int nf=0;nf<4;++nf)
                    #pragma unroll
                    for (int j=0;j<4;++j) oacc[mf][nf][j] *= am[mf][j];
        }
        #pragma unroll
        for (int qi=0;qi<2;++qi){
            float m = mrow[qi];
            float rs = 0.f;
            #pragma unroll
            for (int kf=0;kf<4;++kf){
                #pragma unroll
                for (int j=0;j<4;++j){
                    float e = __builtin_amdgcn_exp2f(sc[kf][qi][j] - m);
                    sc[kf][qi][j] = e;
                    rs += e;
                }
            }
            rs += __shfl_xor(rs,16);
            rs += __shfl_xor(rs,32);
            lrow[qi] += rs;
        }
        #pragma unroll
        for (int kf=0;kf<4;++kf)
            #pragma unroll
            for (int qi=0;qi<2;++qi){
                u16x4 pk;
                pk.x = f2h_bits(sc[kf][qi][0]);
                pk.y = f2h_bits(sc[kf][qi][1]);
                pk.z = f2h_bits(sc[kf][qi][2]);
                pk.w = f2h_bits(sc[kf][qi][3]);
                *reinterpret_cast<u16x4*>(&plds[qi*16+lr][kf*16+lg*4]) = pk;
            }
        asm volatile("s_waitcnt lgkmcnt(0)" ::: "memory");
        __builtin_amdgcn_sched_barrier(0);

        half8 pa[2][2];
        #pragma unroll
        for (int mf=0;mf<2;++mf)
            #pragma unroll
            for (int kh=0;kh<2;++kh)
                pa[mf][kh] = *reinterpret_cast<const half8*>(&plds[mf*16+lr][kh*32 + lg*8]);
        __builtin_amdgcn_s_setprio(1);
        #pragma unroll
        for (int mf=0;mf<2;++mf)
            #pragma unroll
            for (int nf=0;nf<4;++nf)
                #pragma unroll
                for (int kh=0;kh<2;++kh)
                    oacc[mf][nf] = __builtin_amdgcn_mfma_f32_16x16x32_f16(pa[mf][kh], vf[nf][kh], oacc[mf][nf], 0,0,0);
        __builtin_amdgcn_s_setprio(0);
    }

    float linv[2][4];
    #pragma unroll
    for (int mf=0;mf<2;++mf)
        #pragma unroll
        for (int j=0;j<4;++j) linv[mf][j] = 1.0f/__shfl(lrow[mf], lg*4+j);
    #pragma unroll
    for (int mf=0;mf<2;++mf)
        #pragma unroll
        for (int nf=0;nf<4;++nf)
            #pragma unroll
            for (int j=0;j<4;++j)
                Mg[(size_t)(b*S_LEN + q0 + mf*16 + lg*4 + j)*D_MODEL + h*HDIM + nf*16 + lr]
                    = f2h_bits(oacc[mf][nf][j]*linv[mf][j]);
}

extern "C" void kernel_launch(void* const* d_in, const int* in_sizes, int n_in,
                              void* d_out, int out_size, void* d_ws, size_t ws_size,
                              hipStream_t stream) {
    const float* x    = (const float*)d_in[0];
    const float* wqkv = (const float*)d_in[1];
    const float* wout = (const float*)d_in[2];
    float* out = (float*)d_out;
    char* ws = (char*)d_ws;

    const size_t MB = 1u<<20;
    u16* xh     = (u16*)(ws + 0*MB);
    u16* wqkvT  = (u16*)(ws + 8*MB);
    u16* woutT  = (u16*)(ws + 14*MB);
    u16* Qh     = (u16*)(ws + 16*MB);
    u16* Kh     = (u16*)(ws + 24*MB);
    u16* Vt     = (u16*)(ws + 32*MB);
    u16* Mg     = (u16*)(ws + 40*MB);

    k_cvt_x <<<4096, 256, 0, stream>>>(x, xh);
    k_cvt_wT<<<dim3(96,32), 256, 0, stream>>>(wqkv, wqkvT, 1024, 3072);
    k_cvt_wT<<<dim3(32,32), 256, 0, stream>>>(wout, woutT, 1024, 1024);
    k_gemm<1><<<768, 256, 0, stream>>>(xh, wqkvT, nullptr, Qh, Kh, Vt);   // 32 m x 24 n tiles
    k_attn  <<<2048, 64, 0, stream>>>(Qh, Kh, Vt, Mg);
    k_gemm<0><<<256, 256, 0, stream>>>(Mg, woutT, out, nullptr, nullptr, nullptr); // 32 m x 8 n
}